// Round 1
// 368.324 us; speedup vs baseline: 1.0055x; 1.0055x over previous
//
#include <hip/hip_runtime.h>
#include <hip/hip_bf16.h>

#define BATCH 512
#define NN 256

// ---------------------------------------------------------------------------
// Kernel 1: column means in fp32 replicating NUMPY PAIRWISE SUMMATION
// association bit-for-bit (numpy add.reduce binary-reduce inner loop over the
// reduction axis, pairwise_sum_FLOAT):
//   n=256 -> split 128+128 (blocks sequential);
//   each 128-block: r[t] = a[t] + a[8+t] + a[16+t] + ... + a[120+t]
//   (8 interleaved accumulators, m ascending), combined
//   ((r0+r1)+(r2+r3)) + ((r4+r5)+(r6+r7));
//   total = blockL + blockR; mean = total / 256 (exact pow2 scale).
// Additions only -> default strict FP keeps our explicit order.
//
// RESTRUCTURED FOR OCCUPANCY (prev: 64-thread blocks, 1 wave/SIMD, 10%
// occupancy, latency-bound at 2.7 TB/s aggregate): one THREAD per column
// (scalar loads), 256-thread blocks -> 4 waves/block, 4096 waves total
// (~16 waves/CU). A wave reads 64 consecutive floats per k-step (256 B,
// fully coalesced); 8 independent accumulator chains per lane preserve MLP.
// Per-column add order is IDENTICAL to the previous float4 version, so the
// result is bit-exact.
// ---------------------------------------------------------------------------
__global__ __launch_bounds__(256) void col_means_kernel(
    const float* __restrict__ D1, const float* __restrict__ D2,
    float* __restrict__ am, float* __restrict__ bm) {
  const int b = blockIdx.x;
  const float* __restrict__ src = blockIdx.y ? D2 : D1;
  float* __restrict__ dst = blockIdx.y ? bm : am;
  const int c = threadIdx.x;  // 0..255, one column per thread

  const float* base = src + (size_t)b * (NN * NN) + c;

  float half_sum[2];
#pragma unroll
  for (int h = 0; h < 2; ++h) {
    const float* hbase = base + (size_t)(h * 128) * NN;
    float r[8];
    // r[t] = a[t]
#pragma unroll
    for (int t = 0; t < 8; ++t) r[t] = hbase[(size_t)t * NN];
    // r[t] += a[8m + t], m = 1..15 ascending
    for (int m = 1; m < 16; ++m) {
#pragma unroll
      for (int t = 0; t < 8; ++t) r[t] += hbase[(size_t)(8 * m + t) * NN];
    }
    // ((r0+r1)+(r2+r3)) + ((r4+r5)+(r6+r7))
    const float s01 = r[0] + r[1];
    const float s23 = r[2] + r[3];
    const float s45 = r[4] + r[5];
    const float s67 = r[6] + r[7];
    half_sum[h] = (s01 + s23) + (s45 + s67);
  }
  const float tot = half_sum[0] + half_sum[1];
  dst[(size_t)b * NN + c] = tot * (1.0f / 256.0f);  // exact pow2 scale
}

// ---------------------------------------------------------------------------
// Kernel 2: exact stable lexsort via ranking (fp32 keys). Thread i counts how
// many j have (type_j, value_j, j) < (type_i, value_i, i) — a strict total
// order, so ranks are a permutation and exactly reproduce stable np.lexsort
// (type primary, value secondary, index tie-break — handles exact fp32 ties).
// ord1[rank] = atom, ord2[rank] = slot, perm[ord2[k]] = ord1[k].
// LDS reads are wave-broadcast (all lanes read the same j) — conflict-free.
// ---------------------------------------------------------------------------
__global__ __launch_bounds__(256) void rank_perm_kernel(
    const float* __restrict__ am, const float* __restrict__ bm,
    const int* __restrict__ t1, const int* __restrict__ t2,
    int* __restrict__ perm, float* __restrict__ types_out) {
  const int b = blockIdx.x;
  const int tid = threadIdx.x;

  __shared__ float va[NN];
  __shared__ int ta[NN];
  __shared__ int ord1[NN];
  __shared__ int ord2[NN];
  __shared__ int plds[NN];

  // ---- side A: rank (t1, a, idx) ----
  va[tid] = am[b * NN + tid];
  ta[tid] = t1[b * NN + tid];
  __syncthreads();
  {
    const float vi = va[tid];
    const int ti = ta[tid];
    int r = 0;
#pragma unroll 4
    for (int j = 0; j < NN; ++j) {
      const int tj = ta[j];
      const float vj = va[j];
      const bool less =
          (tj < ti) || (tj == ti && (vj < vi || (vj == vi && j < tid)));
      r += less ? 1 : 0;
    }
    ord1[r] = tid;
  }
  __syncthreads();

  // ---- side B: rank (t2, b, idx) ----
  va[tid] = bm[b * NN + tid];
  ta[tid] = t2[b * NN + tid];
  __syncthreads();
  {
    const float vi = va[tid];
    const int ti = ta[tid];
    int r = 0;
#pragma unroll 4
    for (int j = 0; j < NN; ++j) {
      const int tj = ta[j];
      const float vj = va[j];
      const bool less =
          (tj < ti) || (tj == ti && (vj < vi || (vj == vi && j < tid)));
      r += less ? 1 : 0;
    }
    ord2[r] = tid;
  }
  __syncthreads();

  // perm[ord2[k]] = ord1[k]
  plds[ord2[tid]] = ord1[tid];
  __syncthreads();

  perm[b * NN + tid] = plds[tid];
  types_out[b * NN + tid] = (float)t1[b * NN + plds[tid]];
}

// ---------------------------------------------------------------------------
// Kernel 3: out[b,i,j] = D1[b, perm[i], perm[j]].
// One block handles 4 output rows of one batch (one wave per row).
// Source row staged coalesced (float4) into LDS; column permutation done as
// LDS gather (random perm -> low-way bank aliasing, ~free); float4 stores.
// ---------------------------------------------------------------------------
__global__ __launch_bounds__(256) void reorder_kernel(
    const float* __restrict__ D1, const int* __restrict__ perm,
    float* __restrict__ out) {
  const int b = blockIdx.x >> 6;
  const int ig = blockIdx.x & 63;
  const int tid = threadIdx.x;
  const int lane = tid & 63;
  const int w = tid >> 6;

  __shared__ int plds[NN];
  __shared__ float4 rows[4][64];

  plds[tid] = perm[b * NN + tid];
  __syncthreads();

  const int i = ig * 4 + w;
  const int pi = plds[i];
  const float* rsrc = D1 + ((size_t)b * NN + pi) * NN;
  rows[w][lane] = *(const float4*)(rsrc + 4 * lane);
  __syncthreads();

  const float* rf = (const float*)&rows[w][0];
  const int j0 = 4 * lane;
  float4 o;
  o.x = rf[plds[j0 + 0]];
  o.y = rf[plds[j0 + 1]];
  o.z = rf[plds[j0 + 2]];
  o.w = rf[plds[j0 + 3]];
  *(float4*)(out + ((size_t)b * NN + i) * NN + j0) = o;
}

extern "C" void kernel_launch(void* const* d_in, const int* in_sizes, int n_in,
                              void* d_out, int out_size, void* d_ws, size_t ws_size,
                              hipStream_t stream) {
  const float* D1 = (const float*)d_in[0];
  const float* D2 = (const float*)d_in[1];
  const int* t1 = (const int*)d_in[2];
  const int* t2 = (const int*)d_in[3];

  float* out = (float*)d_out;                       // [B,N,N] fp32
  float* types_out = out + (size_t)BATCH * NN * NN; // [B,N] written as fp32

  // workspace: a-means f32 [B*N], b-means f32 [B*N], perm i32 [B*N]
  float* am = (float*)d_ws;
  float* bm = am + (size_t)BATCH * NN;
  int* perm = (int*)(bm + (size_t)BATCH * NN);

  col_means_kernel<<<dim3(BATCH, 2), 256, 0, stream>>>(D1, D2, am, bm);
  rank_perm_kernel<<<BATCH, 256, 0, stream>>>(am, bm, t1, t2, perm, types_out);
  reorder_kernel<<<BATCH * 64, 256, 0, stream>>>(D1, perm, out);
}

// Round 2
// 345.975 us; speedup vs baseline: 1.0704x; 1.0646x over previous
//
#include <hip/hip_runtime.h>
#include <hip/hip_bf16.h>

#define BATCH 512
#define NN 256

// ---------------------------------------------------------------------------
// FUSED kernel: one block per batch (512 threads = 8 waves).
//
// Phase A: column means of D1[b] and D2[b], replicating NUMPY PAIRWISE
//   SUMMATION bit-for-bit. Per column: 16 chains r_t (t=0..7, halves h=0,1),
//   r_t = ((a[t]+a[8+t])+a[16+t])+... (m ascending, serial);
//   half_h = ((r0+r1)+(r2+r3)) + ((r4+r5)+(r6+r7)); tot = half0+half1; /256.
//   Distribution: thread = (c4 = tid&63 -> float4 columns 4*c4..+3,
//   slot = tid>>6). slot -> {mat = slot>>2, h = (slot&3)>>1, tq = slot&1}.
//   Each slot computes chains t = 4*tq..4*tq+3 and the partial
//   (r0'+r1')+(r2'+r3'); halves and total combined via LDS with the exact
//   original association. Only additions -> strict FP order preserved.
//   => float4 loads + 16 waves/CU + 4 independent chains/thread.
//
// Phase B: exact stable lexsort via ranking (identical predicate to the
//   verified 3-kernel version); sides A/B ranked concurrently by the two
//   halves of the block. perm stays in LDS.
//
// Phase C: out[b,i,j] = D1[b, perm[i], perm[j]]. Wave w owns rows
//   i = 8*iter + w. Source row staged to LDS via register prefetch
//   (issue next row's global load before gathering current -> latency
//   hidden under LDS gather + store). Column indices plds[4*lane+k] are
//   loop-invariant -> hoisted to registers once. D1 re-read has short reuse
//   distance (same block) -> L3/L2 hits instead of HBM.
// ---------------------------------------------------------------------------
__device__ __forceinline__ float4 f4add(float4 x, float4 y) {
  return make_float4(x.x + y.x, x.y + y.y, x.z + y.z, x.w + y.w);
}

__global__ __launch_bounds__(512, 4) void fused_hungarian_kernel(
    const float* __restrict__ D1, const float* __restrict__ D2,
    const int* __restrict__ t1, const int* __restrict__ t2,
    float* __restrict__ out, float* __restrict__ types_out) {
  const int b = blockIdx.x;
  const int tid = threadIdx.x;

  __shared__ float4 partial4[2][4][64];  // [mat][h*2+tq][c4]
  __shared__ float va[NN], vb[NN];
  __shared__ int ta[NN], tb[NN];
  __shared__ int ord1[NN], ord2[NN], plds[NN];
  __shared__ float4 rows[8][64];

  // ---------------- Phase A: accumulate chains ----------------
  {
    const int c4 = tid & 63;
    const int slot = tid >> 6;      // 0..7
    const int mat = slot >> 2;      // 0: D1, 1: D2
    const int s2 = slot & 3;        // h*2 + tq
    const int h = s2 >> 1;
    const int tq = s2 & 1;
    const float* __restrict__ src = (mat ? D2 : D1) + (size_t)b * (NN * NN);
    const float* cb = src + (size_t)(h * 128 + 4 * tq) * NN + 4 * c4;

    // chains t = 4*tq + k, k = 0..3; r_k serial over m (ascending)
    float4 r0 = *(const float4*)(cb + (size_t)0 * NN);
    float4 r1 = *(const float4*)(cb + (size_t)1 * NN);
    float4 r2 = *(const float4*)(cb + (size_t)2 * NN);
    float4 r3 = *(const float4*)(cb + (size_t)3 * NN);
#pragma unroll
    for (int m = 1; m < 16; ++m) {
      const float* p = cb + (size_t)(8 * m) * NN;
      r0 = f4add(r0, *(const float4*)(p + (size_t)0 * NN));
      r1 = f4add(r1, *(const float4*)(p + (size_t)1 * NN));
      r2 = f4add(r2, *(const float4*)(p + (size_t)2 * NN));
      r3 = f4add(r3, *(const float4*)(p + (size_t)3 * NN));
    }
    // slot partial: (r0+r1)+(r2+r3)  ==  (s_{t0,t1}) + (s_{t2,t3})
    partial4[mat][s2][c4] = f4add(f4add(r0, r1), f4add(r2, r3));
  }
  // stage types into LDS (independent of phase A)
  if (tid < NN) ta[tid] = t1[b * NN + tid];
  else          tb[tid - NN] = t2[b * NN + (tid - NN)];
  __syncthreads();

  // ---------------- combine means (exact tree) ----------------
  {
    const int mat = tid >> 8;  // 0/1
    const int c = tid & 255;
    const float p0 = ((const float*)partial4[mat][0])[c];
    const float p1 = ((const float*)partial4[mat][1])[c];
    const float p2 = ((const float*)partial4[mat][2])[c];
    const float p3 = ((const float*)partial4[mat][3])[c];
    // half0 = (s01+s23)+(s45+s67) for h=0 is p0+p1; h=1 is p2+p3
    const float tot = (p0 + p1) + (p2 + p3);
    const float mean = tot * (1.0f / 256.0f);  // exact pow2 scale
    if (mat == 0) va[c] = mean; else vb[c] = mean;
  }
  __syncthreads();

  // ---------------- Phase B: rank both sides concurrently ----------------
  {
    const int side = tid >> 8;  // 0: (t1, a), 1: (t2, b)
    const int c = tid & 255;
    const float* __restrict__ vv = side ? vb : va;
    const int* __restrict__ tt = side ? tb : ta;
    const float vi = vv[c];
    const int ti = tt[c];
    int r = 0;
#pragma unroll 4
    for (int j = 0; j < NN; ++j) {
      const int tj = tt[j];
      const float vj = vv[j];
      const bool less =
          (tj < ti) || (tj == ti && (vj < vi || (vj == vi && j < c)));
      r += less ? 1 : 0;
    }
    if (side == 0) ord1[r] = c;
    else           ord2[r] = c;
  }
  __syncthreads();
  if (tid < NN) plds[ord2[tid]] = ord1[tid];  // perm[ord2[k]] = ord1[k]
  __syncthreads();
  if (tid < NN) types_out[b * NN + tid] = (float)ta[plds[tid]];

  // ---------------- Phase C: symmetric reorder ----------------
  {
    const int w = tid >> 6;     // wave 0..7
    const int lane = tid & 63;
    const int j0 = 4 * lane;
    // loop-invariant column-gather indices
    const int pj0 = plds[j0 + 0];
    const int pj1 = plds[j0 + 1];
    const int pj2 = plds[j0 + 2];
    const int pj3 = plds[j0 + 3];
    const float* __restrict__ Db = D1 + (size_t)b * (NN * NN);
    float* __restrict__ outb = out + (size_t)b * (NN * NN);
    const float* rowf = (const float*)&rows[w][0];

    // prologue: stage first row for this wave
    int pi = plds[w];
    float4 vst = *(const float4*)(Db + (size_t)pi * NN + j0);
    for (int iter = 0; iter < 32; ++iter) {
      const int i = iter * 8 + w;
      rows[w][lane] = vst;  // ds_write staged row (wave-private buffer)
      if (iter < 31) {      // issue next row's load before consuming current
        const int pin = plds[(iter + 1) * 8 + w];
        vst = *(const float4*)(Db + (size_t)pin * NN + j0);
      }
      float4 o;
      o.x = rowf[pj0];
      o.y = rowf[pj1];
      o.z = rowf[pj2];
      o.w = rowf[pj3];
      *(float4*)(outb + (size_t)i * NN + j0) = o;
    }
  }
}

extern "C" void kernel_launch(void* const* d_in, const int* in_sizes, int n_in,
                              void* d_out, int out_size, void* d_ws, size_t ws_size,
                              hipStream_t stream) {
  const float* D1 = (const float*)d_in[0];
  const float* D2 = (const float*)d_in[1];
  const int* t1 = (const int*)d_in[2];
  const int* t2 = (const int*)d_in[3];

  float* out = (float*)d_out;                        // [B,N,N] fp32
  float* types_out = out + (size_t)BATCH * NN * NN;  // [B,N] written as fp32

  fused_hungarian_kernel<<<BATCH, 512, 0, stream>>>(D1, D2, t1, t2, out,
                                                    types_out);
}

// Round 3
// 343.214 us; speedup vs baseline: 1.0791x; 1.0080x over previous
//
#include <hip/hip_runtime.h>

#define BATCH 512
#define NN 256

typedef __attribute__((ext_vector_type(4))) float f32x4;

__device__ __forceinline__ float4 f4add(float4 x, float4 y) {
  return make_float4(x.x + y.x, x.y + y.y, x.z + y.z, x.w + y.w);
}

// One DMA instruction stages one full 1 KB row: 64 lanes x 16 B.
// Global source is per-lane; LDS dest is wave-uniform base (+ lane*16 in HW).
__device__ __forceinline__ void dma_row16(const float* g, float* l) {
  __builtin_amdgcn_global_load_lds(
      (const __attribute__((address_space(1))) void*)g,
      (__attribute__((address_space(3))) void*)l, 16, 0, 0);
}

// ---------------------------------------------------------------------------
// FUSED kernel: one block per batch (512 threads = 8 waves). LDS union:
//   [0,64K):  phase-A stage: 8 waves x 8 row-slots x 1 KB   (ring, depth 2)
//             after phase A (post-barrier reuse):
//             va@0 vb@1K ta@2K tb@3K ord1@4K ord2@5K plds@6K rows@8K..16K
//   [64K,72K): partial sums [2][4][256] f32 (never aliased)
//
// Phase A (bit-exact numpy pairwise summation, same association as verified
//   rounds): wave (mat,h,tq) owns rows h*128+4tq+8m+k. NEW: rows staged via
//   global_load_lds ring with counted vmcnt (prologue 8 rows, steady-state
//   vmcnt(4), lgkmcnt(0) guards slot WAR before re-issue). No VGPR round
//   trip -> 8 KB/wave in flight (vs ~48 B/lane before), no barriers.
//   Thread reads its float4 column slice of each row from LDS; add chains
//   r_k += row(m,k), m ascending; partial (r0+r1)+(r2+r3); combine tree
//   (p0+p1)+(p2+p3) == (half0)+(half1); *1/256. Values identical -> exact.
//
// Phase B: stable lexsort via ranking, sides concurrent (unchanged).
//
// Phase C: out[b,i,j] = D1[b,perm[i],perm[j]]; wave w rows i=8*iter+w.
//   NEW: 2-deep register prefetch (load latency ~1000 cy now covered by
//   two iterations of gather+store), nontemporal output stores (output is
//   never re-read; preserves D1/input L3 residency).
// ---------------------------------------------------------------------------
__global__ __launch_bounds__(512, 4) void fused_hungarian_kernel(
    const float* __restrict__ D1, const float* __restrict__ D2,
    const int* __restrict__ t1, const int* __restrict__ t2,
    float* __restrict__ out, float* __restrict__ types_out) {
  const int b = blockIdx.x;
  const int tid = threadIdx.x;
  const int lane = tid & 63;
  const int wv = tid >> 6;

  __shared__ __align__(16) char smem[73728];
  float* const stagef = (float*)smem;
  float* const va = (float*)smem;
  float* const vb = (float*)(smem + 1024);
  int* const ta = (int*)(smem + 2048);
  int* const tb = (int*)(smem + 3072);
  int* const ord1 = (int*)(smem + 4096);
  int* const ord2 = (int*)(smem + 5120);
  int* const plds = (int*)(smem + 6144);
  float4* const rows = (float4*)(smem + 8192);     // [8][64] float4
  float* const partialf = (float*)(smem + 65536);  // [2][4][256] f32

  // ---------------- Phase A: DMA-staged column sums ----------------
  {
    const int mat = wv >> 2;  // 0: D1, 1: D2
    const int s2 = wv & 3;    // h*2 + tq
    const int h = s2 >> 1;
    const int tq = s2 & 1;
    const float* __restrict__ src = (mat ? D2 : D1) + (size_t)b * (NN * NN);
    const float* cb = src + (size_t)(h * 128 + 4 * tq) * NN;
    float* const wstage = stagef + wv * 2048;  // 8 slots x 256 floats

    // prologue: m = 0 (slots 0-3), m = 1 (slots 4-7) -> 8 outstanding
#pragma unroll
    for (int mk = 0; mk < 8; ++mk) {
      const int m = mk >> 2, k = mk & 3;
      dma_row16(cb + (size_t)(8 * m + k) * NN + 4 * lane,
                wstage + ((m & 1) * 4 + k) * 256);
    }

    float4 r0, r1, r2, r3;
#pragma unroll
    for (int m = 0; m < 16; ++m) {
      if (m == 15) asm volatile("s_waitcnt vmcnt(0)" ::: "memory");
      else         asm volatile("s_waitcnt vmcnt(4)" ::: "memory");
      const float* sp = wstage + (m & 1) * 1024 + 4 * lane;
      const float4 v0 = *(const float4*)(sp + 0);
      const float4 v1 = *(const float4*)(sp + 256);
      const float4 v2 = *(const float4*)(sp + 512);
      const float4 v3 = *(const float4*)(sp + 768);
      // retire the ds_reads before re-issuing DMA into the same slots (WAR)
      asm volatile("s_waitcnt lgkmcnt(0)" ::: "memory");
      if (m + 2 < 16) {
#pragma unroll
        for (int k = 0; k < 4; ++k)
          dma_row16(cb + (size_t)(8 * (m + 2) + k) * NN + 4 * lane,
                    wstage + ((m & 1) * 4 + k) * 256);
      }
      if (m == 0) { r0 = v0; r1 = v1; r2 = v2; r3 = v3; }
      else {
        r0 = f4add(r0, v0); r1 = f4add(r1, v1);
        r2 = f4add(r2, v2); r3 = f4add(r3, v3);
      }
    }
    // slot partial: (r0+r1)+(r2+r3); partialf region never aliases stage
    const float4 part = f4add(f4add(r0, r1), f4add(r2, r3));
    *(float4*)(partialf + (mat * 4 + s2) * 256 + 4 * lane) = part;
  }
  __syncthreads();  // stage region dead; partials published

  // ---------------- combine means (exact tree) + stage types ----------------
  {
    const int mat = tid >> 8;  // 0/1
    const int c = tid & 255;
    const float p0 = partialf[(mat * 4 + 0) * 256 + c];
    const float p1 = partialf[(mat * 4 + 1) * 256 + c];
    const float p2 = partialf[(mat * 4 + 2) * 256 + c];
    const float p3 = partialf[(mat * 4 + 3) * 256 + c];
    // (p0+p1) = half0, (p2+p3) = half1; tot = half0 + half1
    const float mean = ((p0 + p1) + (p2 + p3)) * (1.0f / 256.0f);
    if (mat == 0) { va[c] = mean; ta[c] = t1[b * NN + c]; }
    else          { vb[c] = mean; tb[c] = t2[b * NN + c]; }
  }
  __syncthreads();

  // ---------------- Phase B: rank both sides concurrently ----------------
  {
    const int side = tid >> 8;  // 0: (t1, a), 1: (t2, b)
    const int c = tid & 255;
    const float* __restrict__ vv = side ? vb : va;
    const int* __restrict__ tt = side ? tb : ta;
    const float vi = vv[c];
    const int ti = tt[c];
    int r = 0;
#pragma unroll 4
    for (int j = 0; j < NN; ++j) {
      const int tj = tt[j];
      const float vj = vv[j];
      const bool less =
          (tj < ti) || (tj == ti && (vj < vi || (vj == vi && j < c)));
      r += less ? 1 : 0;
    }
    if (side == 0) ord1[r] = c;
    else           ord2[r] = c;
  }
  __syncthreads();
  if (tid < NN) plds[ord2[tid]] = ord1[tid];  // perm[ord2[k]] = ord1[k]
  __syncthreads();
  if (tid < NN) types_out[b * NN + tid] = (float)ta[plds[tid]];

  // ---------------- Phase C: symmetric reorder (2-deep prefetch) ----------
  {
    const int j0 = 4 * lane;
    const int pj0 = plds[j0 + 0];
    const int pj1 = plds[j0 + 1];
    const int pj2 = plds[j0 + 2];
    const int pj3 = plds[j0 + 3];
    const float* __restrict__ Db = D1 + (size_t)b * (NN * NN);
    float* __restrict__ outb = out + (size_t)b * (NN * NN);
    const float* const rowf = (const float*)(rows + wv * 64);

    float4 vA = *(const float4*)(Db + (size_t)plds[wv] * NN + j0);
    float4 vB = *(const float4*)(Db + (size_t)plds[8 + wv] * NN + j0);
#pragma unroll 4
    for (int iter = 0; iter < 32; ++iter) {
      rows[wv * 64 + lane] = vA;  // wave-private; same-wave LDS order
      vA = vB;
      if (iter + 2 < 32)
        vB = *(const float4*)(Db + (size_t)plds[(iter + 2) * 8 + wv] * NN + j0);
      float4 o;
      o.x = rowf[pj0];
      o.y = rowf[pj1];
      o.z = rowf[pj2];
      o.w = rowf[pj3];
      __builtin_nontemporal_store(
          *(const f32x4*)&o,
          (f32x4*)(outb + (size_t)(iter * 8 + wv) * NN + j0));
    }
  }
}

extern "C" void kernel_launch(void* const* d_in, const int* in_sizes, int n_in,
                              void* d_out, int out_size, void* d_ws, size_t ws_size,
                              hipStream_t stream) {
  const float* D1 = (const float*)d_in[0];
  const float* D2 = (const float*)d_in[1];
  const int* t1 = (const int*)d_in[2];
  const int* t2 = (const int*)d_in[3];

  float* out = (float*)d_out;                        // [B,N,N] fp32
  float* types_out = out + (size_t)BATCH * NN * NN;  // [B,N] written as fp32

  fused_hungarian_kernel<<<BATCH, 512, 0, stream>>>(D1, D2, t1, t2, out,
                                                    types_out);
}